// Round 2
// baseline (16235.333 us; speedup 1.0000x reference)
//
#include <hip/hip_runtime.h>
#include <hip/hip_bf16.h>
#include <math.h>

// Problem constants
#define B_ 8
#define N_ 1025
#define C_ 3200
#define H_ 25
#define D_ 128
#define M_ (B_ * N_)       // 8200 rows
#define C3_ (3 * C_)       // 9600
#define MPAD_ 8320         // 65 * 128
#define KP_ 9600           // K' = 3*C for split-bf16 GEMMs

typedef unsigned short u16;
typedef short bf16x8 __attribute__((ext_vector_type(8)));
typedef float f32x4 __attribute__((ext_vector_type(4)));
typedef short s8x16 __attribute__((ext_vector_type(8)));

// round-to-nearest-even fp32 -> bf16 bits
__device__ inline u16 f2bf(float f) {
    unsigned u = __float_as_uint(f);
    u += 0x7FFFu + ((u >> 16) & 1u);
    return (u16)(u >> 16);
}

__device__ inline void load_lds16(const void* g, void* s) {
    __builtin_amdgcn_global_load_lds(
        (const __attribute__((address_space(1))) void*)g,
        (__attribute__((address_space(3))) void*)s, 16, 0, 0);
}

// ---------------------------------------------------------------------------
// conv_split_A: fp32 [M,3200] -> bf16 [Mpad, 9600] as [hi | lo | hi] K-blocks.
// One thread per 8 elements. Rows >= M zero-filled.
// ---------------------------------------------------------------------------
__global__ __launch_bounds__(256) void conv_split_A(
    const float* __restrict__ src, u16* __restrict__ dst)
{
    int idx = blockIdx.x * 256 + threadIdx.x;          // Mpad*400 threads
    if (idx >= MPAD_ * 400) return;
    int m = idx / 400;
    int k = (idx - m * 400) * 8;
    u16 hi[8], lo[8];
    if (m < M_) {
        const float* p = src + (size_t)m * C_ + k;
        #pragma unroll
        for (int j = 0; j < 8; ++j) {
            float x = p[j];
            u16 h = f2bf(x);
            float hf = __uint_as_float(((unsigned)h) << 16);
            hi[j] = h;
            lo[j] = f2bf(x - hf);
        }
    } else {
        #pragma unroll
        for (int j = 0; j < 8; ++j) { hi[j] = 0; lo[j] = 0; }
    }
    u16* d = dst + (size_t)m * KP_ + k;
    *(bf16x8*)(d)         = *(bf16x8*)hi;
    *(bf16x8*)(d + C_)    = *(bf16x8*)lo;
    *(bf16x8*)(d + 2*C_)  = *(bf16x8*)hi;
}

// ---------------------------------------------------------------------------
// conv_split_B: fp32 W [3200, Nn] row-major -> bf16 [Nn, 9600] transposed,
// K-blocks [hi | hi | lo].  64x64 tile transpose through LDS.
// grid: (Nn/64, 3200/64)
// ---------------------------------------------------------------------------
__global__ __launch_bounds__(256) void conv_split_B(
    const float* __restrict__ W, u16* __restrict__ dst, int Nn)
{
    __shared__ float Ts[64][65];
    const int tid = threadIdx.x;
    const int n0 = blockIdx.x * 64;
    const int k0 = blockIdx.y * 64;

    #pragma unroll
    for (int p = 0; p < 16; ++p) {
        int kl = p * 4 + (tid >> 6);
        int nl = tid & 63;
        Ts[nl][kl] = W[(size_t)(k0 + kl) * Nn + n0 + nl];
    }
    __syncthreads();

    #pragma unroll
    for (int pass = 0; pass < 2; ++pass) {
        int nl = (tid >> 3) + pass * 32;
        int kg = (tid & 7) * 8;
        u16 hi[8], lo[8];
        #pragma unroll
        for (int j = 0; j < 8; ++j) {
            float x = Ts[nl][kg + j];
            u16 h = f2bf(x);
            float hf = __uint_as_float(((unsigned)h) << 16);
            hi[j] = h;
            lo[j] = f2bf(x - hf);
        }
        u16* d = dst + (size_t)(n0 + nl) * KP_ + (k0 + kg);
        *(bf16x8*)(d)        = *(bf16x8*)hi;
        *(bf16x8*)(d + C_)   = *(bf16x8*)hi;
        *(bf16x8*)(d + 2*C_) = *(bf16x8*)lo;
    }
}

// ---------------------------------------------------------------------------
// MFMA GEMM: C[M,N] = A'[Mpad,KP] @ B'[N,KP]^T + bias.
// 128x128 tile, BK=32, 256 threads (4 waves 2x2), 16x16x32 bf16 MFMA.
// global_load_lds width-16 staging (m97 structure).
// ---------------------------------------------------------------------------
__global__ __launch_bounds__(256) void gemm_bt_bf16(
    const u16* __restrict__ A, const u16* __restrict__ Bt,
    const float* __restrict__ bias, float* __restrict__ C,
    int M, int N)
{
    __shared__ u16 As[128 * 32];
    __shared__ u16 Bs[128 * 32];

    const int tid  = threadIdx.x;
    const int lane = tid & 63;
    const int w    = tid >> 6;
    const int wm   = w & 1, wn = w >> 1;
    const int rowBase = blockIdx.y * 128;
    const int colBase = blockIdx.x * 128;

    // staging chunks: c = t*256 + w*64 + lane; row = c>>2; elem off = (c&3)*8
    const int c0 = w * 64 + lane;
    const int c1 = c0 + 256;
    const int r0 = c0 >> 2, o0 = (c0 & 3) * 8;
    const int r1 = c1 >> 2, o1 = (c1 & 3) * 8;
    u16* ldsA0 = &As[(w * 64) * 8];          // wave-uniform bases
    u16* ldsA1 = &As[(256 + w * 64) * 8];
    u16* ldsB0 = &Bs[(w * 64) * 8];
    u16* ldsB1 = &Bs[(256 + w * 64) * 8];

    const u16* Ab = A  + (size_t)rowBase * KP_;
    const u16* Bb = Bt + (size_t)colBase * KP_;

    const int lr = lane & 15, lg = lane >> 4;

    f32x4 acc[4][4] = {};

    for (int k0 = 0; k0 < KP_; k0 += 32) {
        load_lds16(Ab + (size_t)r0 * KP_ + k0 + o0, ldsA0);
        load_lds16(Ab + (size_t)r1 * KP_ + k0 + o1, ldsA1);
        load_lds16(Bb + (size_t)r0 * KP_ + k0 + o0, ldsB0);
        load_lds16(Bb + (size_t)r1 * KP_ + k0 + o1, ldsB1);
        __syncthreads();

        bf16x8 af[4], bfr[4];
        #pragma unroll
        for (int i = 0; i < 4; ++i) {
            af[i]  = *(const bf16x8*)&As[(wm * 64 + i * 16 + lr) * 32 + lg * 8];
            bfr[i] = *(const bf16x8*)&Bs[(wn * 64 + i * 16 + lr) * 32 + lg * 8];
        }
        #pragma unroll
        for (int i = 0; i < 4; ++i)
            #pragma unroll
            for (int j = 0; j < 4; ++j)
                acc[i][j] = __builtin_amdgcn_mfma_f32_16x16x32_bf16(
                    af[i], bfr[j], acc[i][j], 0, 0, 0);
        __syncthreads();
    }

    #pragma unroll
    for (int i = 0; i < 4; ++i) {
        #pragma unroll
        for (int j = 0; j < 4; ++j) {
            int gc = colBase + wn * 64 + j * 16 + lr;
            float bv = bias[gc];
            #pragma unroll
            for (int r = 0; r < 4; ++r) {
                int gr = rowBase + wm * 64 + i * 16 + lg * 4 + r;
                if (gr < M) C[(size_t)gr * N + gc] = acc[i][j][r] + bv;
            }
        }
    }
}

// ---------------------------------------------------------------------------
// fp32 fallback GEMM (used only if workspace too small)
// ---------------------------------------------------------------------------
__global__ __launch_bounds__(256) void gemm_bias_f32(
    const float* __restrict__ A, const float* __restrict__ Bm,
    const float* __restrict__ bias, float* __restrict__ C,
    int M, int N, int K)
{
    __shared__ float As[16][68];
    __shared__ float Bs[16][68];
    const int tid = threadIdx.x;
    const int tx = tid & 15;
    const int ty = tid >> 4;
    const int rowBase = blockIdx.y * 64;
    const int colBase = blockIdx.x * 64;
    float acc[4][4] = {};
    for (int k0 = 0; k0 < K; k0 += 16) {
        #pragma unroll
        for (int l = 0; l < 4; ++l) {
            int idx = tid + l * 256;
            int i = idx >> 4, kk = idx & 15;
            int gr = rowBase + i;
            As[kk][i] = (gr < M) ? A[(size_t)gr * K + k0 + kk] : 0.f;
        }
        #pragma unroll
        for (int l = 0; l < 4; ++l) {
            int idx = tid + l * 256;
            int kk = idx >> 6, j = idx & 63;
            int gc = colBase + j;
            Bs[kk][j] = (gc < N) ? Bm[(size_t)(k0 + kk) * N + gc] : 0.f;
        }
        __syncthreads();
        #pragma unroll
        for (int kk = 0; kk < 16; ++kk) {
            float4 a4 = *(const float4*)&As[kk][ty * 4];
            float4 b4 = *(const float4*)&Bs[kk][tx * 4];
            float ar[4] = {a4.x, a4.y, a4.z, a4.w};
            float br[4] = {b4.x, b4.y, b4.z, b4.w};
            #pragma unroll
            for (int i = 0; i < 4; ++i)
                #pragma unroll
                for (int j = 0; j < 4; ++j)
                    acc[i][j] += ar[i] * br[j];
        }
        __syncthreads();
    }
    #pragma unroll
    for (int i = 0; i < 4; ++i) {
        int gr = rowBase + ty * 4 + i;
        if (gr >= M) continue;
        #pragma unroll
        for (int j = 0; j < 4; ++j) {
            int gc = colBase + tx * 4 + j;
            if (gc < N) C[(size_t)gr * N + gc] = acc[i][j] + bias[gc];
        }
    }
}

// ---------------------------------------------------------------------------
// RMSNorm over full C=3200 for q and k slices.
// ---------------------------------------------------------------------------
__global__ __launch_bounds__(256) void rmsnorm_kernel(
    float* __restrict__ qkv, const float* __restrict__ qw,
    const float* __restrict__ kw)
{
    const int row   = blockIdx.x >> 1;
    const int which = blockIdx.x & 1;
    float* p = qkv + (size_t)row * C3_ + which * C_;
    const float* w = which ? kw : qw;
    const int tid = threadIdx.x;

    float ss = 0.f;
    for (int i = tid; i < C_; i += 256) {
        float v = p[i];
        ss += v * v;
    }
    #pragma unroll
    for (int off = 32; off; off >>= 1) ss += __shfl_down(ss, off);

    __shared__ float wsum[4];
    __shared__ float stot;
    if ((tid & 63) == 0) wsum[tid >> 6] = ss;
    __syncthreads();
    if (tid == 0) stot = wsum[0] + wsum[1] + wsum[2] + wsum[3];
    __syncthreads();

    const float scale = rsqrtf(stot / (float)C_ + 1e-6f);
    for (int i = tid; i < C_; i += 256) p[i] = p[i] * scale * w[i];
}

// ---------------------------------------------------------------------------
// Flash attention (fp32): one block = 32 queries of one (b,h).
// ---------------------------------------------------------------------------
#define FA_LDV 132

__global__ __launch_bounds__(256) void flash_kernel(
    const float* __restrict__ qkv, float* __restrict__ attn_out)
{
    __shared__ float Qs[32][FA_LDV];
    __shared__ float Ks[32][FA_LDV];
    __shared__ float Vs[32][FA_LDV];
    __shared__ float Ps[32][33];

    const int b  = blockIdx.z;
    const int h  = blockIdx.y;
    const int q0 = blockIdx.x * 32;
    const int tid = threadIdx.x;
    const int r = tid >> 3;
    const int g = tid & 7;
    const float scale = 0.088388347648318447f;

    #pragma unroll
    for (int l = 0; l < 16; ++l) {
        int idx = tid + l * 256;
        int i = idx >> 7, d = idx & 127;
        int q = q0 + i;
        Qs[i][d] = (q < N_) ? qkv[((size_t)(b * N_ + q)) * C3_ + h * D_ + d] * scale
                            : 0.f;
    }

    float4 o0 = {0,0,0,0}, o1 = {0,0,0,0}, o2 = {0,0,0,0}, o3 = {0,0,0,0};
    float m = -INFINITY, l_sum = 0.f;

    const int nkt = (N_ + 31) / 32;
    for (int kt = 0; kt < nkt; ++kt) {
        const int k0 = kt * 32;
        __syncthreads();
        #pragma unroll
        for (int l = 0; l < 16; ++l) {
            int idx = tid + l * 256;
            int i = idx >> 7, d = idx & 127;
            int kk = k0 + i;
            if (kk < N_) {
                size_t base = ((size_t)(b * N_ + kk)) * C3_ + h * D_ + d;
                Ks[i][d] = qkv[base + C_];
                Vs[i][d] = qkv[base + 2 * C_];
            } else {
                Ks[i][d] = 0.f;
                Vs[i][d] = 0.f;
            }
        }
        __syncthreads();

        const int c0 = g * 4;
        float s0 = 0.f, s1 = 0.f, s2 = 0.f, s3 = 0.f;
        #pragma unroll 4
        for (int d = 0; d < D_; d += 4) {
            float4 qv = *(const float4*)&Qs[r][d];
            float4 ka = *(const float4*)&Ks[c0 + 0][d];
            float4 kb = *(const float4*)&Ks[c0 + 1][d];
            float4 kc = *(const float4*)&Ks[c0 + 2][d];
            float4 kd = *(const float4*)&Ks[c0 + 3][d];
            s0 += qv.x*ka.x + qv.y*ka.y + qv.z*ka.z + qv.w*ka.w;
            s1 += qv.x*kb.x + qv.y*kb.y + qv.z*kb.z + qv.w*kb.w;
            s2 += qv.x*kc.x + qv.y*kc.y + qv.z*kc.z + qv.w*kc.w;
            s3 += qv.x*kd.x + qv.y*kd.y + qv.z*kd.z + qv.w*kd.w;
        }
        if (k0 + c0 + 0 >= N_) s0 = -INFINITY;
        if (k0 + c0 + 1 >= N_) s1 = -INFINITY;
        if (k0 + c0 + 2 >= N_) s2 = -INFINITY;
        if (k0 + c0 + 3 >= N_) s3 = -INFINITY;

        float mloc = fmaxf(fmaxf(s0, s1), fmaxf(s2, s3));
        #pragma unroll
        for (int off = 1; off < 8; off <<= 1)
            mloc = fmaxf(mloc, __shfl_xor(mloc, off));
        float mnew  = fmaxf(m, mloc);
        float alpha = __expf(m - mnew);
        float p0 = __expf(s0 - mnew), p1 = __expf(s1 - mnew);
        float p2 = __expf(s2 - mnew), p3 = __expf(s3 - mnew);
        float ls = p0 + p1 + p2 + p3;
        #pragma unroll
        for (int off = 1; off < 8; off <<= 1) ls += __shfl_xor(ls, off);
        l_sum = l_sum * alpha + ls;
        m = mnew;

        o0.x *= alpha; o0.y *= alpha; o0.z *= alpha; o0.w *= alpha;
        o1.x *= alpha; o1.y *= alpha; o1.z *= alpha; o1.w *= alpha;
        o2.x *= alpha; o2.y *= alpha; o2.z *= alpha; o2.w *= alpha;
        o3.x *= alpha; o3.y *= alpha; o3.z *= alpha; o3.w *= alpha;

        Ps[r][c0 + 0] = p0; Ps[r][c0 + 1] = p1;
        Ps[r][c0 + 2] = p2; Ps[r][c0 + 3] = p3;
        __syncthreads();

        const int dbase = g * 16;
        #pragma unroll 8
        for (int c = 0; c < 32; ++c) {
            float p = Ps[r][c];
            const float* vp = &Vs[c][dbase];
            float4 va = *(const float4*)(vp + 0);
            float4 vb = *(const float4*)(vp + 4);
            float4 vc = *(const float4*)(vp + 8);
            float4 vd = *(const float4*)(vp + 12);
            o0.x += p*va.x; o0.y += p*va.y; o0.z += p*va.z; o0.w += p*va.w;
            o1.x += p*vb.x; o1.y += p*vb.y; o1.z += p*vb.z; o1.w += p*vb.w;
            o2.x += p*vc.x; o2.y += p*vc.y; o2.z += p*vc.z; o2.w += p*vc.w;
            o3.x += p*vd.x; o3.y += p*vd.y; o3.z += p*vd.z; o3.w += p*vd.w;
        }
    }

    const int q = q0 + r;
    if (q < N_) {
        float inv = 1.f / l_sum;
        o0.x *= inv; o0.y *= inv; o0.z *= inv; o0.w *= inv;
        o1.x *= inv; o1.y *= inv; o1.z *= inv; o1.w *= inv;
        o2.x *= inv; o2.y *= inv; o2.z *= inv; o2.w *= inv;
        o3.x *= inv; o3.y *= inv; o3.z *= inv; o3.w *= inv;
        float* op = attn_out + ((size_t)(b * N_ + q)) * C_ + h * D_ + g * 16;
        *(float4*)(op + 0)  = o0;
        *(float4*)(op + 4)  = o1;
        *(float4*)(op + 8)  = o2;
        *(float4*)(op + 12) = o3;
    }
}

// ---------------------------------------------------------------------------
extern "C" void kernel_launch(void* const* d_in, const int* in_sizes, int n_in,
                              void* d_out, int out_size, void* d_ws, size_t ws_size,
                              hipStream_t stream)
{
    const float* x        = (const float*)d_in[0];
    const float* qkv_w    = (const float*)d_in[1];
    const float* qkv_b    = (const float*)d_in[2];
    const float* q_norm_w = (const float*)d_in[3];
    const float* k_norm_w = (const float*)d_in[4];
    const float* proj_w   = (const float*)d_in[5];
    const float* proj_b   = (const float*)d_in[6];
    float* out = (float*)d_out;

    const size_t QKV_BYTES  = (size_t)M_ * C3_ * 4;       // 314,880,000
    const size_t ATTN_BYTES = (size_t)M_ * C_ * 4;        // 104,960,000
    const size_t A_BYTES    = (size_t)MPAD_ * KP_ * 2;    // 159,744,000
    const size_t B_BYTES    = (size_t)C3_ * KP_ * 2;      // 184,320,000
    const size_t REQ = QKV_BYTES + ATTN_BYTES + A_BYTES + B_BYTES;

    char* ws = (char*)d_ws;
    float* qkv      = (float*)ws;
    float* attn_out = (float*)(ws + QKV_BYTES);

    dim3 blk(256);

    if (ws_size >= REQ) {
        u16* Abuf = (u16*)(ws + QKV_BYTES + ATTN_BYTES);
        u16* Bbuf = (u16*)(ws + QKV_BYTES + ATTN_BYTES + A_BYTES);

        // 1) convert x and qkv_w
        int convA_blocks = (MPAD_ * 400 + 255) / 256;
        conv_split_A<<<convA_blocks, blk, 0, stream>>>(x, Abuf);
        conv_split_B<<<dim3(C3_ / 64, C_ / 64), blk, 0, stream>>>(qkv_w, Bbuf, C3_);

        // 2) QKV GEMM (MFMA)
        gemm_bt_bf16<<<dim3(C3_ / 128, MPAD_ / 128), blk, 0, stream>>>(
            Abuf, Bbuf, qkv_b, qkv, M_, C3_);

        // 3) RMSNorm
        rmsnorm_kernel<<<dim3(M_ * 2), blk, 0, stream>>>(qkv, q_norm_w, k_norm_w);

        // 4) Flash attention
        flash_kernel<<<dim3((N_ + 31) / 32, H_, B_), blk, 0, stream>>>(qkv, attn_out);

        // 5) convert attn_out and proj_w (reuse buffers)
        conv_split_A<<<convA_blocks, blk, 0, stream>>>(attn_out, Abuf);
        conv_split_B<<<dim3(C_ / 64, C_ / 64), blk, 0, stream>>>(proj_w, Bbuf, C_);

        // 6) proj GEMM (MFMA)
        gemm_bt_bf16<<<dim3(C_ / 128, MPAD_ / 128), blk, 0, stream>>>(
            Abuf, Bbuf, proj_b, out, M_, C_);
    } else {
        // fp32 fallback
        gemm_bias_f32<<<dim3(C3_ / 64, (M_ + 63) / 64), blk, 0, stream>>>(
            x, qkv_w, qkv_b, qkv, M_, C3_, C_);
        rmsnorm_kernel<<<dim3(M_ * 2), blk, 0, stream>>>(qkv, q_norm_w, k_norm_w);
        flash_kernel<<<dim3((N_ + 31) / 32, H_, B_), blk, 0, stream>>>(qkv, attn_out);
        gemm_bias_f32<<<dim3(C_ / 64, (M_ + 63) / 64), blk, 0, stream>>>(
            attn_out, proj_w, proj_b, out, M_, C_, C_);
    }
}

// Round 3
// 8752.367 us; speedup vs baseline: 1.8550x; 1.8550x over previous
//
#include <hip/hip_runtime.h>
#include <hip/hip_bf16.h>
#include <math.h>

// Problem constants
#define B_ 8
#define N_ 1025
#define C_ 3200
#define H_ 25
#define D_ 128
#define M_ (B_ * N_)       // 8200 rows
#define C3_ (3 * C_)       // 9600

typedef unsigned short u16;
typedef unsigned int u32;
typedef short bf16x8 __attribute__((ext_vector_type(8)));
typedef float f32x4 __attribute__((ext_vector_type(4)));

__device__ inline void load_lds16(const void* g, void* s) {
    __builtin_amdgcn_global_load_lds(
        (const __attribute__((address_space(1))) void*)g,
        (__attribute__((address_space(3))) void*)s, 16, 0, 0);
}

// Split two fp32 into packed bf16 hi + packed bf16 lo (x0 in low half).
__device__ inline void split_pair(float x0, float x1, u32& hpk, u32& lpk) {
    __hip_bfloat162 h2 = __float22bfloat162_rn(float2{x0, x1});
    union { __hip_bfloat162 b; u32 u; } cv; cv.b = h2;
    u32 h = cv.u;
    float hf0 = __uint_as_float(h << 16);
    float hf1 = __uint_as_float(h & 0xFFFF0000u);
    __hip_bfloat162 l2 = __float22bfloat162_rn(float2{x0 - hf0, x1 - hf1});
    union { __hip_bfloat162 b; u32 u; } cl; cl.b = l2;
    hpk = h; lpk = cl.u;
}

// ---------------------------------------------------------------------------
// Fused split-bf16 MFMA GEMM: C[M,N] = A[M,K=3200] @ B[3200,N] + bias.
// A: fp32 row-major. B: fp32 row-major (k-major).
// 128x128 tile, BK=32, 256 threads (4 waves, 2x2), 16x16x32 bf16 MFMA.
// 3-term split: Ah*Bh + Al*Bh + Ah*Bl  (error ~2^-17 relative).
// B staged fp32 via global_load_lds; fragments converted in-wave.
// A staged through registers with conversion to bf16 hi/lo LDS tiles.
// ---------------------------------------------------------------------------
__global__ __launch_bounds__(256) void gemm_split(
    const float* __restrict__ A, const float* __restrict__ Bm,
    const float* __restrict__ bias, float* __restrict__ Cc,
    int M, int N)
{
    __shared__ u16  As_hi[128 * 32];
    __shared__ u16  As_lo[128 * 32];
    __shared__ float Bf[32 * 128];

    const int tid  = threadIdx.x;
    const int lane = tid & 63;
    const int w    = tid >> 6;
    const int wm   = w & 1, wn = w >> 1;
    const int rowBase = blockIdx.y * 128;
    const int colBase = blockIdx.x * 128;
    const int lr = lane & 15, lg = lane >> 4;

    // A staging: pass p handles row p*32 + (tid>>3), k-chunk (tid&7)*4
    const int ar = tid >> 3;
    const int ak = (tid & 7) * 4;

    f32x4 acc[4][4] = {};

    for (int k0 = 0; k0 < C_; k0 += 32) {
        // ---- B tile: 32 k-rows x 128 cols fp32, direct global->LDS ----
        #pragma unroll
        for (int p = 0; p < 4; ++p) {
            int c = p * 256 + tid;                  // 16B chunk index
            const float* g = Bm + (size_t)(k0 + (c >> 5)) * N
                                + colBase + (c & 31) * 4;
            load_lds16(g, &Bf[(p * 256 + w * 64) * 4]);   // wave-uniform base
        }
        // ---- A tile: fp32 -> (hi,lo) bf16 LDS [row][32] ----
        #pragma unroll
        for (int p = 0; p < 4; ++p) {
            int r  = p * 32 + ar;
            int gr = rowBase + r; if (gr >= M) gr = M - 1;
            float4 a4 = *(const float4*)(A + (size_t)gr * C_ + k0 + ak);
            u32 h0, h1, l0, l1;
            split_pair(a4.x, a4.y, h0, l0);
            split_pair(a4.z, a4.w, h1, l1);
            *(uint2*)&As_hi[r * 32 + ak] = make_uint2(h0, h1);
            *(uint2*)&As_lo[r * 32 + ak] = make_uint2(l0, l1);
        }
        __syncthreads();

        // ---- fragments + MFMA ----
        bf16x8 ah[4], al[4];
        #pragma unroll
        for (int i = 0; i < 4; ++i) {
            ah[i] = *(const bf16x8*)&As_hi[(wm * 64 + i * 16 + lr) * 32 + lg * 8];
            al[i] = *(const bf16x8*)&As_lo[(wm * 64 + i * 16 + lr) * 32 + lg * 8];
        }
        #pragma unroll
        for (int j = 0; j < 4; ++j) {
            const float* bp = &Bf[(lg * 8) * 128 + wn * 64 + j * 16 + lr];
            union { u32 u[4]; bf16x8 v; } BH, BL;
            split_pair(bp[0 * 128], bp[1 * 128], BH.u[0], BL.u[0]);
            split_pair(bp[2 * 128], bp[3 * 128], BH.u[1], BL.u[1]);
            split_pair(bp[4 * 128], bp[5 * 128], BH.u[2], BL.u[2]);
            split_pair(bp[6 * 128], bp[7 * 128], BH.u[3], BL.u[3]);
            #pragma unroll
            for (int i = 0; i < 4; ++i)
                acc[i][j] = __builtin_amdgcn_mfma_f32_16x16x32_bf16(
                    ah[i], BH.v, acc[i][j], 0, 0, 0);
            #pragma unroll
            for (int i = 0; i < 4; ++i)
                acc[i][j] = __builtin_amdgcn_mfma_f32_16x16x32_bf16(
                    al[i], BH.v, acc[i][j], 0, 0, 0);
            #pragma unroll
            for (int i = 0; i < 4; ++i)
                acc[i][j] = __builtin_amdgcn_mfma_f32_16x16x32_bf16(
                    ah[i], BL.v, acc[i][j], 0, 0, 0);
        }
        __syncthreads();
    }

    // ---- epilogue: C/D layout col=lane&15, row=(lane>>4)*4+reg ----
    #pragma unroll
    for (int i = 0; i < 4; ++i) {
        #pragma unroll
        for (int j = 0; j < 4; ++j) {
            int gc = colBase + wn * 64 + j * 16 + lr;
            float bv = bias[gc];
            #pragma unroll
            for (int r = 0; r < 4; ++r) {
                int gr = rowBase + wm * 64 + i * 16 + lg * 4 + r;
                if (gr < M) Cc[(size_t)gr * N + gc] = acc[i][j][r] + bv;
            }
        }
    }
}

// ---------------------------------------------------------------------------
// RMSNorm over full C=3200 for q and k slices.
// ---------------------------------------------------------------------------
__global__ __launch_bounds__(256) void rmsnorm_kernel(
    float* __restrict__ qkv, const float* __restrict__ qw,
    const float* __restrict__ kw)
{
    const int row   = blockIdx.x >> 1;
    const int which = blockIdx.x & 1;
    float* p = qkv + (size_t)row * C3_ + which * C_;
    const float* w = which ? kw : qw;
    const int tid = threadIdx.x;

    float ss = 0.f;
    for (int i = tid; i < C_; i += 256) {
        float v = p[i];
        ss += v * v;
    }
    #pragma unroll
    for (int off = 32; off; off >>= 1) ss += __shfl_down(ss, off);

    __shared__ float wsum[4];
    __shared__ float stot;
    if ((tid & 63) == 0) wsum[tid >> 6] = ss;
    __syncthreads();
    if (tid == 0) stot = wsum[0] + wsum[1] + wsum[2] + wsum[3];
    __syncthreads();

    const float scale = rsqrtf(stot / (float)C_ + 1e-6f);
    for (int i = tid; i < C_; i += 256) p[i] = p[i] * scale * w[i];
}

// ---------------------------------------------------------------------------
// Flash attention (fp32): one block = 32 queries of one (b,h).
// ---------------------------------------------------------------------------
#define FA_LDV 132

__global__ __launch_bounds__(256) void flash_kernel(
    const float* __restrict__ qkv, float* __restrict__ attn_out)
{
    __shared__ float Qs[32][FA_LDV];
    __shared__ float Ks[32][FA_LDV];
    __shared__ float Vs[32][FA_LDV];
    __shared__ float Ps[32][33];

    const int b  = blockIdx.z;
    const int h  = blockIdx.y;
    const int q0 = blockIdx.x * 32;
    const int tid = threadIdx.x;
    const int r = tid >> 3;
    const int g = tid & 7;
    const float scale = 0.088388347648318447f;

    #pragma unroll
    for (int l = 0; l < 16; ++l) {
        int idx = tid + l * 256;
        int i = idx >> 7, d = idx & 127;
        int q = q0 + i;
        Qs[i][d] = (q < N_) ? qkv[((size_t)(b * N_ + q)) * C3_ + h * D_ + d] * scale
                            : 0.f;
    }

    float4 o0 = {0,0,0,0}, o1 = {0,0,0,0}, o2 = {0,0,0,0}, o3 = {0,0,0,0};
    float m = -INFINITY, l_sum = 0.f;

    const int nkt = (N_ + 31) / 32;
    for (int kt = 0; kt < nkt; ++kt) {
        const int k0 = kt * 32;
        __syncthreads();
        #pragma unroll
        for (int l = 0; l < 16; ++l) {
            int idx = tid + l * 256;
            int i = idx >> 7, d = idx & 127;
            int kk = k0 + i;
            if (kk < N_) {
                size_t base = ((size_t)(b * N_ + kk)) * C3_ + h * D_ + d;
                Ks[i][d] = qkv[base + C_];
                Vs[i][d] = qkv[base + 2 * C_];
            } else {
                Ks[i][d] = 0.f;
                Vs[i][d] = 0.f;
            }
        }
        __syncthreads();

        const int c0 = g * 4;
        float s0 = 0.f, s1 = 0.f, s2 = 0.f, s3 = 0.f;
        #pragma unroll 4
        for (int d = 0; d < D_; d += 4) {
            float4 qv = *(const float4*)&Qs[r][d];
            float4 ka = *(const float4*)&Ks[c0 + 0][d];
            float4 kb = *(const float4*)&Ks[c0 + 1][d];
            float4 kc = *(const float4*)&Ks[c0 + 2][d];
            float4 kd = *(const float4*)&Ks[c0 + 3][d];
            s0 += qv.x*ka.x + qv.y*ka.y + qv.z*ka.z + qv.w*ka.w;
            s1 += qv.x*kb.x + qv.y*kb.y + qv.z*kb.z + qv.w*kb.w;
            s2 += qv.x*kc.x + qv.y*kc.y + qv.z*kc.z + qv.w*kc.w;
            s3 += qv.x*kd.x + qv.y*kd.y + qv.z*kd.z + qv.w*kd.w;
        }
        if (k0 + c0 + 0 >= N_) s0 = -INFINITY;
        if (k0 + c0 + 1 >= N_) s1 = -INFINITY;
        if (k0 + c0 + 2 >= N_) s2 = -INFINITY;
        if (k0 + c0 + 3 >= N_) s3 = -INFINITY;

        float mloc = fmaxf(fmaxf(s0, s1), fmaxf(s2, s3));
        #pragma unroll
        for (int off = 1; off < 8; off <<= 1)
            mloc = fmaxf(mloc, __shfl_xor(mloc, off));
        float mnew  = fmaxf(m, mloc);
        float alpha = __expf(m - mnew);
        float p0 = __expf(s0 - mnew), p1 = __expf(s1 - mnew);
        float p2 = __expf(s2 - mnew), p3 = __expf(s3 - mnew);
        float ls = p0 + p1 + p2 + p3;
        #pragma unroll
        for (int off = 1; off < 8; off <<= 1) ls += __shfl_xor(ls, off);
        l_sum = l_sum * alpha + ls;
        m = mnew;

        o0.x *= alpha; o0.y *= alpha; o0.z *= alpha; o0.w *= alpha;
        o1.x *= alpha; o1.y *= alpha; o1.z *= alpha; o1.w *= alpha;
        o2.x *= alpha; o2.y *= alpha; o2.z *= alpha; o2.w *= alpha;
        o3.x *= alpha; o3.y *= alpha; o3.z *= alpha; o3.w *= alpha;

        Ps[r][c0 + 0] = p0; Ps[r][c0 + 1] = p1;
        Ps[r][c0 + 2] = p2; Ps[r][c0 + 3] = p3;
        __syncthreads();

        const int dbase = g * 16;
        #pragma unroll 8
        for (int c = 0; c < 32; ++c) {
            float p = Ps[r][c];
            const float* vp = &Vs[c][dbase];
            float4 va = *(const float4*)(vp + 0);
            float4 vb = *(const float4*)(vp + 4);
            float4 vc = *(const float4*)(vp + 8);
            float4 vd = *(const float4*)(vp + 12);
            o0.x += p*va.x; o0.y += p*va.y; o0.z += p*va.z; o0.w += p*va.w;
            o1.x += p*vb.x; o1.y += p*vb.y; o1.z += p*vb.z; o1.w += p*vb.w;
            o2.x += p*vc.x; o2.y += p*vc.y; o2.z += p*vc.z; o2.w += p*vc.w;
            o3.x += p*vd.x; o3.y += p*vd.y; o3.z += p*vd.z; o3.w += p*vd.w;
        }
    }

    const int q = q0 + r;
    if (q < N_) {
        float inv = 1.f / l_sum;
        o0.x *= inv; o0.y *= inv; o0.z *= inv; o0.w *= inv;
        o1.x *= inv; o1.y *= inv; o1.z *= inv; o1.w *= inv;
        o2.x *= inv; o2.y *= inv; o2.z *= inv; o2.w *= inv;
        o3.x *= inv; o3.y *= inv; o3.z *= inv; o3.w *= inv;
        float* op = attn_out + ((size_t)(b * N_ + q)) * C_ + h * D_ + g * 16;
        *(float4*)(op + 0)  = o0;
        *(float4*)(op + 4)  = o1;
        *(float4*)(op + 8)  = o2;
        *(float4*)(op + 12) = o3;
    }
}

// ---------------------------------------------------------------------------
extern "C" void kernel_launch(void* const* d_in, const int* in_sizes, int n_in,
                              void* d_out, int out_size, void* d_ws, size_t ws_size,
                              hipStream_t stream)
{
    const float* x        = (const float*)d_in[0];
    const float* qkv_w    = (const float*)d_in[1];
    const float* qkv_b    = (const float*)d_in[2];
    const float* q_norm_w = (const float*)d_in[3];
    const float* k_norm_w = (const float*)d_in[4];
    const float* proj_w   = (const float*)d_in[5];
    const float* proj_b   = (const float*)d_in[6];
    float* out = (float*)d_out;

    // workspace: qkv fp32 (315 MB) + attn_out fp32 (105 MB) = 420 MB
    float* qkv      = (float*)d_ws;
    float* attn_out = qkv + (size_t)M_ * C3_;

    dim3 blk(256);

    // 1) QKV GEMM (fused split-bf16 MFMA): [8200,3200] @ [3200,9600] + bias
    gemm_split<<<dim3(C3_ / 128, (M_ + 127) / 128), blk, 0, stream>>>(
        x, qkv_w, qkv_b, qkv, M_, C3_);

    // 2) RMSNorm on q and k slices
    rmsnorm_kernel<<<dim3(M_ * 2), blk, 0, stream>>>(qkv, q_norm_w, k_norm_w);

    // 3) Flash attention
    flash_kernel<<<dim3((N_ + 31) / 32, H_, B_), blk, 0, stream>>>(qkv, attn_out);

    // 4) Output projection (fused split-bf16 MFMA): [8200,3200] @ [3200,3200] + bias
    gemm_split<<<dim3(C_ / 128, (M_ + 127) / 128), blk, 0, stream>>>(
        attn_out, proj_w, proj_b, out, M_, C_);
}